// Round 3
// baseline (74.398 us; speedup 1.0000x reference)
//
#include <hip/hip_runtime.h>
#include <math.h>

// Bit-exact-to-numpy float32 helpers: block fp contraction (HIP defaults to
// -ffp-contract=fast; an fma vs mul+add 1-ulp difference can flip the
// ns=ceil(seg/0.2) quantization or the ld>=0 / vt1>=0 light-hit decisions,
// which move a pixel by up to ~0.07 — over the 1.84e-2 threshold).
// DECISION CHAIN IS FROZEN: a,b,disc,x1,x2,seg,ns,step,t,pc,lb,lc,ld,lsq,vt1
// replicate the reference op-for-op (CR div/sqrt per HIP default
// -fhip-fp32-correctly-rounded-divide-sqrt). __expf feeds continuous outputs
// only. Only bitwise-identity simplifications allowed (see shade1 notes).
__device__ __forceinline__ float fmulr(float a, float b) { return __fmul_rn(a, b); }
__device__ __forceinline__ float faddr(float a, float b) { return __fadd_rn(a, b); }
__device__ __forceinline__ float fsubr(float a, float b) { return __fsub_rn(a, b); }

struct Col { float x, y, z; };

// ---- Specialized path: center=(0,0,0), radius=1 (the actual scene) ----
// Bitwise identities vs generic: b = 2*(rdz*3) [x+(-0)=x]; cc = 8 exact;
// rr = 1 exact; pcx = t*rdx, pcy = t*rdy (+-0 diff dies in squares and in
// -lb+lsq since lsq>0); pcz = 3 + t*rdz.
//
// R3 change: fixed 10-iteration fully-unrolled BRANCH-FREE march.
//   - ns <= 10 guaranteed: seg = chord of unit sphere <= 2 (+ ~1e-6 fp slop),
//     0.2f = 0.20000000298 > 0.2, so seg/0.2f < 10 => ceil <= 10.
//   - predication (k<ns)&(ld>=0)&(vt1>=0) with "+ 0.0f" else-value is
//     bit-identical to the reference's where()+sum (x+0.0f == x, order kept).
//   - iterations are data-independent (t from k, not incremental) => unroll
//     lets the scheduler interleave them: latency-bound -> issue-bound.
__device__ __forceinline__ Col shade1(float rdx, float rdy, float rdz)
{
    const float BGx = 0.572f, BGy = 0.772f, BGz = 0.921f;
    Col out = {BGx, BGy, BGz};

    float a = faddr(faddr(fmulr(rdx, rdx), fmulr(rdy, rdy)), fmulr(rdz, rdz));
    float b = fmulr(2.0f, fmulr(rdz, 3.0f));
    float disc = fsubr(fmulr(b, b), fmulr(fmulr(4.0f, a), 8.0f));
    if (disc < 0.0f) return out;                 // all-miss wave: execz skip

    float sq = sqrtf(disc > 0.0f ? disc : 1.0f); // CR sqrt, matches np.sqrt
    float twoa = fmulr(2.0f, a);
    float x2 = faddr(-b, sq) / twoa;             // CR div
    if (x2 < 0.0f) return out;
    float x1 = fsubr(-b, sq) / twoa;

    float t0 = fmaxf(x1, 0.0f);
    float t1 = x2;
    float seg = fsubr(t1, t0);
    float ns = ceilf(seg / 0.2f);                // frozen quantization
    float step = seg / fmaxf(ns, 1.0f);          // CR div

    float acc = 0.0f;
#pragma unroll
    for (int k = 0; k < 10; ++k) {
        float t = fsubr(t1, fmulr((float)k + 0.5f, step));
        float pcx = fmulr(t, rdx);
        float pcy = fmulr(t, rdy);
        float pcz = faddr(3.0f, fmulr(t, rdz));
        float lb = fmulr(2.0f, pcy);
        float lc = fsubr(faddr(faddr(fmulr(pcx, pcx), fmulr(pcy, pcy)), fmulr(pcz, pcz)), 1.0f);
        float ld = fsubr(fmulr(lb, lb), fmulr(4.0f, lc));
        float ldg = ld > 0.0f ? ld : 1.0f;       // reference's where(ld>0, ld, 1)
        float lsq = sqrtf(ldg);                  // CR sqrt (vt1>=0 boundary!)
        float vt1 = fmulr(faddr(-lb, lsq), 0.5f);
        bool accept = ((float)k < ns) & (ld >= 0.0f) & (vt1 >= 0.0f);
        float la = __expf(-1.2f * vt1);          // continuous contribution
        acc = faddr(acc, accept ? la : 0.0f);    // == where(mask, la, 0) summed in order
    }

    float sn  = __expf(-0.6f * (step * ns));     // continuous only
    float sn1 = __expf(-0.6f * (step * (ns + 1.0f)));
    float result = 0.6f * step * sn1 * acc;
    out.x = BGx * sn + 1.3f * result;
    out.y = BGy * sn + 0.3f * result;
    out.z = BGz * sn + 0.9f * result;
    return out;
}

// ---- Generic fallback (any scene), numerics identical to round 1/2 ----
__device__ __forceinline__ Col shadeg(float rdx, float rdy, float rdz,
                                      float cx, float cy, float cz,
                                      float rr, float ocx, float ocy, float ocz,
                                      float cc)
{
    const float BGx = 0.572f, BGy = 0.772f, BGz = 0.921f;
    Col out = {BGx, BGy, BGz};

    float a = faddr(faddr(fmulr(rdx, rdx), fmulr(rdy, rdy)), fmulr(rdz, rdz));
    float b = fmulr(2.0f, faddr(faddr(fmulr(rdx, ocx), fmulr(rdy, ocy)), fmulr(rdz, ocz)));
    float disc = fsubr(fmulr(b, b), fmulr(fmulr(4.0f, a), cc));
    if (disc < 0.0f) return out;

    float sq = sqrtf(disc > 0.0f ? disc : 1.0f);
    float twoa = fmulr(2.0f, a);
    float x2 = faddr(-b, sq) / twoa;
    if (x2 < 0.0f) return out;
    float x1 = fsubr(-b, sq) / twoa;

    float t0 = fmaxf(x1, 0.0f);
    float t1 = x2;
    float seg = fsubr(t1, t0);
    float ns = ceilf(seg / 0.2f);
    float step = seg / fmaxf(ns, 1.0f);

    float acc = 0.0f;
    for (int k = 0; k < 12; ++k) {
        float t = fsubr(t1, fmulr((float)k + 0.5f, step));
        float pcx = fsubr(faddr(0.0f, fmulr(t, rdx)), cx);
        float pcy = fsubr(faddr(0.0f, fmulr(t, rdy)), cy);
        float pcz = fsubr(faddr(3.0f, fmulr(t, rdz)), cz);
        float lb = fmulr(2.0f, pcy);
        float lc = fsubr(faddr(faddr(fmulr(pcx, pcx), fmulr(pcy, pcy)), fmulr(pcz, pcz)), rr);
        float ld = fsubr(fmulr(lb, lb), fmulr(4.0f, lc));
        float ldg = ld > 0.0f ? ld : 1.0f;
        float lsq = sqrtf(ldg);
        float vt1 = fmulr(faddr(-lb, lsq), 0.5f);
        bool accept = ((float)k < ns) & (ld >= 0.0f) & (vt1 >= 0.0f);
        float la = __expf(-1.2f * vt1);
        acc = faddr(acc, accept ? la : 0.0f);
    }

    float sn  = __expf(-0.6f * (step * ns));
    float sn1 = __expf(-0.6f * (step * (ns + 1.0f)));
    float result = 0.6f * step * sn1 * acc;
    out.x = BGx * sn + 1.3f * result;
    out.y = BGy * sn + 0.3f * result;
    out.z = BGz * sn + 0.9f * result;
    return out;
}

__global__ __launch_bounds__(256)
void raymarch_kernel(const float* __restrict__ scene,
                     const float* __restrict__ dirs,
                     float* __restrict__ out,
                     int npix)
{
    int p = blockIdx.x * blockDim.x + threadIdx.x;
    if (p >= npix) return;

    float rdx = dirs[3 * p + 0];
    float rdy = dirs[3 * p + 1];
    float rdz = dirs[3 * p + 2];

    // Uniform scalar loads + uniform branch (s_cbranch, no divergence).
    float cx = scene[0], cy = scene[1], cz = scene[2], r = scene[3];

    Col c;
    if (cx == 0.0f && cy == 0.0f && cz == 0.0f && r == 1.0f) {
        c = shade1(rdx, rdy, rdz);
    } else {
        float rr = fmulr(r, r);
        float ocx = fsubr(0.0f, cx);
        float ocy = fsubr(0.0f, cy);
        float ocz = fsubr(3.0f, cz);
        float cc = fsubr(faddr(faddr(fmulr(ocx, ocx), fmulr(ocy, ocy)), fmulr(ocz, ocz)), rr);
        c = shadeg(rdx, rdy, rdz, cx, cy, cz, rr, ocx, ocy, ocz, cc);
    }

    out[3 * p + 0] = c.x;
    out[3 * p + 1] = c.y;
    out[3 * p + 2] = c.z;
}

extern "C" void kernel_launch(void* const* d_in, const int* in_sizes, int n_in,
                              void* d_out, int out_size, void* d_ws, size_t ws_size,
                              hipStream_t stream) {
    const float* scene = (const float*)d_in[0];   // [1,4]: cx,cy,cz,r
    const float* dirs  = (const float*)d_in[1];   // [1024,1024,3] float32
    float* out = (float*)d_out;                   // [1024,1024,3] float32

    int npix = in_sizes[1] / 3;
    dim3 block(256);
    dim3 grid((npix + 255) / 256);
    raymarch_kernel<<<grid, block, 0, stream>>>(scene, dirs, out, npix);
}

// Round 4
// 73.306 us; speedup vs baseline: 1.0149x; 1.0149x over previous
//
#include <hip/hip_runtime.h>
#include <math.h>

// Bit-exact-to-numpy float32 helpers: block fp contraction (HIP defaults to
// -ffp-contract=fast; an fma vs mul+add 1-ulp difference can flip the
// ns=ceil(seg/0.2) quantization or the ld>=0 / vt1>=0 light-hit decisions,
// which move a pixel by up to ~0.07 — over the 1.84e-2 threshold).
// DECISION CHAIN IS FROZEN: a,b,disc,x1,x2,seg,ns,step,t,pc,lb,lc,ld,lsq,vt1
// replicate the reference op-for-op (CR div/sqrt per HIP default). __expf
// feeds continuous outputs only. Only bitwise-identity simplifications
// allowed (see shade1 notes).
__device__ __forceinline__ float fmulr(float a, float b) { return __fmul_rn(a, b); }
__device__ __forceinline__ float faddr(float a, float b) { return __fadd_rn(a, b); }
__device__ __forceinline__ float fsubr(float a, float b) { return __fsub_rn(a, b); }

struct Col { float x, y, z; };

// ---- Specialized path: center=(0,0,0), radius=1 (the actual scene) ----
// Bitwise identities vs generic: b = 2*(rdz*3) [x+(-0)=x]; cc = 8 exact;
// rr = 1 exact; pcx = t*rdx, pcy = t*rdy (+-0 diff dies in squares and in
// -lb+lsq since lsq>0); pcz = 3 + t*rdz.
//
// R4: dynamic-trip march (avg ns≈7 < fixed 10) with a BRANCH-FREE predicated
// body (R2 had two divergent ifs per iteration -> exec-mask save/restore
// overhead; R3's unroll-10 likely blew VGPRs). unroll 2 for modest ILP.
// Predication "+ (accept ? la : 0.0f)" is bit-identical to the reference's
// where()+sum: x + 0.0f == x, summation order preserved.
__device__ __forceinline__ Col shade1(float rdx, float rdy, float rdz)
{
    const float BGx = 0.572f, BGy = 0.772f, BGz = 0.921f;
    Col out = {BGx, BGy, BGz};

    float a = faddr(faddr(fmulr(rdx, rdx), fmulr(rdy, rdy)), fmulr(rdz, rdz));
    float b = fmulr(2.0f, fmulr(rdz, 3.0f));
    float disc = fsubr(fmulr(b, b), fmulr(fmulr(4.0f, a), 8.0f));
    if (disc < 0.0f) return out;                 // miss: lane masked off here

    float sq = sqrtf(disc > 0.0f ? disc : 1.0f); // CR sqrt, matches np.sqrt
    float twoa = fmulr(2.0f, a);
    float x2 = faddr(-b, sq) / twoa;             // CR div
    if (x2 < 0.0f) return out;
    float x1 = fsubr(-b, sq) / twoa;

    float t0 = fmaxf(x1, 0.0f);
    float t1 = x2;
    float seg = fsubr(t1, t0);
    float ns = ceilf(seg / 0.2f);                // frozen quantization
    float step = seg / fmaxf(ns, 1.0f);          // CR div
    int nsi = (int)fminf(ns, 12.0f);             // all k in loop satisfy k<ns

    float acc = 0.0f;
#pragma unroll 2
    for (int k = 0; k < nsi; ++k) {
        float t = fsubr(t1, fmulr((float)k + 0.5f, step));
        float pcx = fmulr(t, rdx);
        float pcy = fmulr(t, rdy);
        float pcz = faddr(3.0f, fmulr(t, rdz));
        float lb = fmulr(2.0f, pcy);
        float lc = fsubr(faddr(faddr(fmulr(pcx, pcx), fmulr(pcy, pcy)), fmulr(pcz, pcz)), 1.0f);
        float ld = fsubr(fmulr(lb, lb), fmulr(4.0f, lc));
        float ldg = ld > 0.0f ? ld : 1.0f;       // reference's where(ld>0, ld, 1)
        float lsq = sqrtf(ldg);                  // CR sqrt (vt1>=0 boundary!)
        float vt1 = fmulr(faddr(-lb, lsq), 0.5f);
        bool accept = (ld >= 0.0f) & (vt1 >= 0.0f);
        float la = __expf(-1.2f * vt1);          // continuous contribution
        acc = faddr(acc, accept ? la : 0.0f);    // == where(mask, la, 0), in order
    }

    float sn  = __expf(-0.6f * (step * ns));     // continuous only
    float sn1 = __expf(-0.6f * (step * (ns + 1.0f)));
    float result = 0.6f * step * sn1 * acc;
    out.x = BGx * sn + 1.3f * result;
    out.y = BGy * sn + 0.3f * result;
    out.z = BGz * sn + 0.9f * result;
    return out;
}

// ---- Generic fallback (any scene), numerics identical to prior rounds ----
__device__ __forceinline__ Col shadeg(float rdx, float rdy, float rdz,
                                      float cx, float cy, float cz,
                                      float rr, float ocx, float ocy, float ocz,
                                      float cc)
{
    const float BGx = 0.572f, BGy = 0.772f, BGz = 0.921f;
    Col out = {BGx, BGy, BGz};

    float a = faddr(faddr(fmulr(rdx, rdx), fmulr(rdy, rdy)), fmulr(rdz, rdz));
    float b = fmulr(2.0f, faddr(faddr(fmulr(rdx, ocx), fmulr(rdy, ocy)), fmulr(rdz, ocz)));
    float disc = fsubr(fmulr(b, b), fmulr(fmulr(4.0f, a), cc));
    if (disc < 0.0f) return out;

    float sq = sqrtf(disc > 0.0f ? disc : 1.0f);
    float twoa = fmulr(2.0f, a);
    float x2 = faddr(-b, sq) / twoa;
    if (x2 < 0.0f) return out;
    float x1 = fsubr(-b, sq) / twoa;

    float t0 = fmaxf(x1, 0.0f);
    float t1 = x2;
    float seg = fsubr(t1, t0);
    float ns = ceilf(seg / 0.2f);
    float step = seg / fmaxf(ns, 1.0f);
    int nsi = (int)fminf(ns, 12.0f);

    float acc = 0.0f;
    for (int k = 0; k < nsi; ++k) {
        float t = fsubr(t1, fmulr((float)k + 0.5f, step));
        float pcx = fsubr(faddr(0.0f, fmulr(t, rdx)), cx);
        float pcy = fsubr(faddr(0.0f, fmulr(t, rdy)), cy);
        float pcz = fsubr(faddr(3.0f, fmulr(t, rdz)), cz);
        float lb = fmulr(2.0f, pcy);
        float lc = fsubr(faddr(faddr(fmulr(pcx, pcx), fmulr(pcy, pcy)), fmulr(pcz, pcz)), rr);
        float ld = fsubr(fmulr(lb, lb), fmulr(4.0f, lc));
        float ldg = ld > 0.0f ? ld : 1.0f;
        float lsq = sqrtf(ldg);
        float vt1 = fmulr(faddr(-lb, lsq), 0.5f);
        bool accept = (ld >= 0.0f) & (vt1 >= 0.0f);
        float la = __expf(-1.2f * vt1);
        acc = faddr(acc, accept ? la : 0.0f);
    }

    float sn  = __expf(-0.6f * (step * ns));
    float sn1 = __expf(-0.6f * (step * (ns + 1.0f)));
    float result = 0.6f * step * sn1 * acc;
    out.x = BGx * sn + 1.3f * result;
    out.y = BGy * sn + 0.3f * result;
    out.z = BGz * sn + 0.9f * result;
    return out;
}

// __launch_bounds__(256, 8): 8 waves/EU forces VGPR <= 64 -> full 32 waves/CU
// occupancy (discriminates the "R3 lost occupancy to VGPRs" hypothesis).
__global__ __launch_bounds__(256, 8)
void raymarch_kernel(const float* __restrict__ scene,
                     const float* __restrict__ dirs,
                     float* __restrict__ out,
                     int npix)
{
    int p = blockIdx.x * blockDim.x + threadIdx.x;
    if (p >= npix) return;

    float rdx = dirs[3 * p + 0];
    float rdy = dirs[3 * p + 1];
    float rdz = dirs[3 * p + 2];

    // Uniform scalar loads + uniform branch (s_cbranch, no divergence).
    float cx = scene[0], cy = scene[1], cz = scene[2], r = scene[3];

    Col c;
    if (cx == 0.0f && cy == 0.0f && cz == 0.0f && r == 1.0f) {
        c = shade1(rdx, rdy, rdz);
    } else {
        float rr = fmulr(r, r);
        float ocx = fsubr(0.0f, cx);
        float ocy = fsubr(0.0f, cy);
        float ocz = fsubr(3.0f, cz);
        float cc = fsubr(faddr(faddr(fmulr(ocx, ocx), fmulr(ocy, ocy)), fmulr(ocz, ocz)), rr);
        c = shadeg(rdx, rdy, rdz, cx, cy, cz, rr, ocx, ocy, ocz, cc);
    }

    out[3 * p + 0] = c.x;
    out[3 * p + 1] = c.y;
    out[3 * p + 2] = c.z;
}

extern "C" void kernel_launch(void* const* d_in, const int* in_sizes, int n_in,
                              void* d_out, int out_size, void* d_ws, size_t ws_size,
                              hipStream_t stream) {
    const float* scene = (const float*)d_in[0];   // [1,4]: cx,cy,cz,r
    const float* dirs  = (const float*)d_in[1];   // [1024,1024,3] float32
    float* out = (float*)d_out;                   // [1024,1024,3] float32

    int npix = in_sizes[1] / 3;
    dim3 block(256);
    dim3 grid((npix + 255) / 256);
    raymarch_kernel<<<grid, block, 0, stream>>>(scene, dirs, out, npix);
}